// Round 6
// baseline (32.284 us; speedup 1.0000x reference)
//
#include <hip/hip_runtime.h>

// DendSN R6: PROBE ROUND.
// Kernel A = exact R2 kernel (best: 19.78 us) -> correctness + baseline.
// Kernel B = ideal-pattern streaming kernel, same footprint (64 MiB read of
// x, 16 MiB write to ws). dur_us(R6) - dur_us(R2) = tB isolates what a
// perfect streaming kernel costs in this harness under identical L3
// conditions -> decides roofline-vs-headroom.

#define TT 8
#define NB 16
#define CC 128
#define BB 4
#define KK 32
#define LL 1024   // H*W

__global__ __launch_bounds__(256, 4) void dendsn_fwd(
    const float* __restrict__ x, const float* __restrict__ k,
    float* __restrict__ out)
{
    const int tid  = threadIdx.x;
    const int lane = tid & 63;
    const int wv   = tid >> 6;
    const int half = lane >> 5;                // 0: compartments {0,1}, 1: {2,3}
    const int sl   = lane & 31;

    const int pairIdx = (blockIdx.x * 4 + wv) * 32 + sl;   // [0, 131072)
    const int l4 = pairIdx & 255;
    const int kk = (pairIdx >> 8) & 31;
    const int n  = pairIdx >> 13;
    const int b0 = half * 2;

    const float k0 = k[0], k1 = k[1], k2 = k[2], k3 = k[3];
    const float m  = fmaxf(fmaxf(k0, k1), fmaxf(k2, k3));
    const float e0 = expf(k0 - m), e1 = expf(k1 - m),
                e2 = expf(k2 - m), e3 = expf(k3 - m);
    const float inv_s = 1.0f / (e0 + e1 + e2 + e3);
    const float fsa[4] = { 3.0f * e0 * inv_s, 3.0f * e1 * inv_s,
                           3.0f * e2 * inv_s, 3.0f * e3 * inv_s };
    const float fs0 = fsa[b0], fs1 = fsa[b0 + 1];

    const float v     = 0.75f + 1e-5f;
    const float inv_v = 1.0f / v;
    const float gs    = 1.0f / sqrtf(2.0f * 3.14159265358979323846f * v);

    const size_t tstride_x = (size_t)NB * CC * LL;
    const size_t tstride_o = (size_t)NB * KK * LL;
    const size_t base_x = ((size_t)n * CC + (size_t)kk * BB + b0) * LL
                        + (size_t)l4 * 4;
    const size_t base_o = ((size_t)n * KK + kk) * LL + (size_t)l4 * 4;

    float pre[2][4];
    float h[4];
    #pragma unroll
    for (int b = 0; b < 2; ++b)
        #pragma unroll
        for (int j = 0; j < 4; ++j) pre[b][j] = 0.0f;
    #pragma unroll
    for (int j = 0; j < 4; ++j) h[j] = 0.0f;

    float4 xv[2], xn[2];
    xv[0] = *reinterpret_cast<const float4*>(x + base_x);
    xv[1] = *reinterpret_cast<const float4*>(x + base_x + LL);

    #pragma unroll
    for (int t = 0; t < TT; ++t) {
        if (t + 1 < TT) {
            const size_t bx = base_x + (size_t)(t + 1) * tstride_x;
            xn[0] = *reinterpret_cast<const float4*>(x + bx);
            xn[1] = *reinterpret_cast<const float4*>(x + bx + LL);
        }

        float y[4];
        #pragma unroll
        for (int j = 0; j < 4; ++j) y[j] = 0.0f;
        #pragma unroll
        for (int b = 0; b < 2; ++b) {
            const float xs[4] = { xv[b].x, xv[b].y, xv[b].z, xv[b].w };
            const float fsb = (b == 0) ? fs0 : fs1;
            #pragma unroll
            for (int j = 0; j < 4; ++j) {
                const float p = 0.5f * pre[b][j] + xs[j];
                pre[b][j] = p;
                const float q = p * p * inv_v;
                const float g = expf(-0.5f * q) * gs;
                y[j] += fsb * ((1.0f - q) * g * inv_v);
            }
        }

        #pragma unroll
        for (int j = 0; j < 4; ++j)
            y[j] += __shfl_xor(y[j], 32);

        float4 o;
        float* op = &o.x;
        #pragma unroll
        for (int j = 0; j < 4; ++j) {
            const float hh = 0.5f * h[j] + y[j];
            const float s  = (hh - 1.0f >= 0.0f) ? 1.0f : 0.0f;
            h[j] = (s != 0.0f) ? 0.0f : hh;
            op[j] = s;
        }
        if (half == 0)
            *reinterpret_cast<float4*>(out + base_o + (size_t)t * tstride_o) = o;

        xv[0] = xn[0];
        xv[1] = xn[1];
    }
}

// Ideal streaming probe: read all 64 MiB of x (wave-contiguous float4, four
// 16 MiB-apart streams per thread), reduce, write 16 MiB to ws. Same
// footprint as the real kernel, perfect access pattern.
__global__ __launch_bounds__(256) void probe_stream(
    const float4* __restrict__ x4, float4* __restrict__ ws4)
{
    const int i = blockIdx.x * 256 + threadIdx.x;   // [0, 1048576)
    const int N = 1048576;                          // total threads
    const float4 a = x4[i];
    const float4 b = x4[i + N];
    const float4 c = x4[i + 2 * N];
    const float4 d = x4[i + 3 * N];
    float4 r;
    r.x = a.x + b.x + c.x + d.x;
    r.y = a.y + b.y + c.y + d.y;
    r.z = a.z + b.z + c.z + d.z;
    r.w = a.w + b.w + c.w + d.w;
    ws4[i] = r;
}

extern "C" void kernel_launch(void* const* d_in, const int* in_sizes, int n_in,
                              void* d_out, int out_size, void* d_ws, size_t ws_size,
                              hipStream_t stream)
{
    const float* x = (const float*)d_in[0];
    const float* k = (const float*)d_in[1];
    float* out = (float*)d_out;

    dendsn_fwd<<<1024, 256, 0, stream>>>(x, k, out);

    // probe: same 80 MiB footprint, ideal pattern, results discarded in ws
    probe_stream<<<4096, 256, 0, stream>>>(
        (const float4*)x, (float4*)d_ws);
}

// Round 7
// 24.935 us; speedup vs baseline: 1.2948x; 1.2948x over previous
//
#include <hip/hip_runtime.h>

// DendSN: dendritic spiking neuron forward.
// x_seq: (T=8, N=16, C=128, H=32, W=32) fp32 ; k: (1,4,1) fp32
// out:   (T=8, N=16, K=32, H=32, W=32) fp32 (0/1 spikes)
//
// R7: R2 (best, 19.78us) + batched split stores. R2 stored per-t with only
// half==0 lanes active (8 half-masked 512B stores inside the serial chain).
// Both compartment-halves hold identical spike values, so: buffer all 8
// spike float4s in regs, then half0 stores even t, half1 stores odd t ->
// 4 full-wave store instructions, store-free serial loop.
// R6 probe established ideal-pattern floor = 12.5us for this footprint.

#define TT 8
#define NB 16
#define CC 128
#define BB 4
#define KK 32
#define LL 1024   // H*W

__global__ __launch_bounds__(256, 4) void dendsn_fwd(
    const float* __restrict__ x, const float* __restrict__ k,
    float* __restrict__ out)
{
    const int tid  = threadIdx.x;
    const int lane = tid & 63;
    const int wv   = tid >> 6;
    const int half = lane >> 5;                // 0: compartments {0,1}, 1: {2,3}
    const int sl   = lane & 31;

    const int pairIdx = (blockIdx.x * 4 + wv) * 32 + sl;   // [0, 131072)
    const int l4 = pairIdx & 255;
    const int kk = (pairIdx >> 8) & 31;
    const int n  = pairIdx >> 13;
    const int b0 = half * 2;

    const float k0 = k[0], k1 = k[1], k2 = k[2], k3 = k[3];
    const float m  = fmaxf(fmaxf(k0, k1), fmaxf(k2, k3));
    const float e0 = expf(k0 - m), e1 = expf(k1 - m),
                e2 = expf(k2 - m), e3 = expf(k3 - m);
    const float inv_s = 1.0f / (e0 + e1 + e2 + e3);
    const float fsa[4] = { 3.0f * e0 * inv_s, 3.0f * e1 * inv_s,
                           3.0f * e2 * inv_s, 3.0f * e3 * inv_s };
    const float fs0 = fsa[b0], fs1 = fsa[b0 + 1];

    const float v     = 0.75f + 1e-5f;
    const float inv_v = 1.0f / v;
    const float gs    = 1.0f / sqrtf(2.0f * 3.14159265358979323846f * v);

    const size_t tstride_x = (size_t)NB * CC * LL;
    const size_t tstride_o = (size_t)NB * KK * LL;
    const size_t base_x = ((size_t)n * CC + (size_t)kk * BB + b0) * LL
                        + (size_t)l4 * 4;
    const size_t base_o = ((size_t)n * KK + kk) * LL + (size_t)l4 * 4;

    float pre[2][4];
    float h[4];
    #pragma unroll
    for (int b = 0; b < 2; ++b)
        #pragma unroll
        for (int j = 0; j < 4; ++j) pre[b][j] = 0.0f;
    #pragma unroll
    for (int j = 0; j < 4; ++j) h[j] = 0.0f;

    float4 xv[2], xn[2];
    xv[0] = *reinterpret_cast<const float4*>(x + base_x);
    xv[1] = *reinterpret_cast<const float4*>(x + base_x + LL);

    float4 obuf[8];   // spike buffer; all indices compile-time (full unroll)

    #pragma unroll
    for (int t = 0; t < TT; ++t) {
        if (t + 1 < TT) {
            const size_t bx = base_x + (size_t)(t + 1) * tstride_x;
            xn[0] = *reinterpret_cast<const float4*>(x + bx);
            xn[1] = *reinterpret_cast<const float4*>(x + bx + LL);
        }

        float y[4];
        #pragma unroll
        for (int j = 0; j < 4; ++j) y[j] = 0.0f;
        #pragma unroll
        for (int b = 0; b < 2; ++b) {
            const float xs[4] = { xv[b].x, xv[b].y, xv[b].z, xv[b].w };
            const float fsb = (b == 0) ? fs0 : fs1;
            #pragma unroll
            for (int j = 0; j < 4; ++j) {
                const float p = 0.5f * pre[b][j] + xs[j];   // alpha decay
                pre[b][j] = p;
                const float q = p * p * inv_v;
                const float g = expf(-0.5f * q) * gs;       // gaussian
                y[j] += fsb * ((1.0f - q) * g * inv_v);     // mexican hat
            }
        }

        // combine halves; both end with identical values (a+b == b+a)
        #pragma unroll
        for (int j = 0; j < 4; ++j)
            y[j] += __shfl_xor(y[j], 32);

        float* op = &obuf[t].x;
        #pragma unroll
        for (int j = 0; j < 4; ++j) {
            const float hh = 0.5f * h[j] + y[j];            // beta decay
            const float s  = (hh - 1.0f >= 0.0f) ? 1.0f : 0.0f;  // heaviside
            h[j] = (s != 0.0f) ? 0.0f : hh;                 // hard reset
            op[j] = s;
        }

        xv[0] = xn[0];
        xv[1] = xn[1];
    }

    // batched split stores: half0 -> even t, half1 -> odd t. Full-wave,
    // 4 instructions total. Both halves hold identical obuf values.
    const size_t base_os = base_o + (size_t)half * tstride_o;
    #pragma unroll
    for (int tp = 0; tp < 4; ++tp) {
        const float4 ov = (half == 0) ? obuf[2 * tp] : obuf[2 * tp + 1];
        *reinterpret_cast<float4*>(
            out + base_os + (size_t)(2 * tp) * tstride_o) = ov;
    }
}

extern "C" void kernel_launch(void* const* d_in, const int* in_sizes, int n_in,
                              void* d_out, int out_size, void* d_ws, size_t ws_size,
                              hipStream_t stream)
{
    const float* x = (const float*)d_in[0];
    const float* k = (const float*)d_in[1];
    float* out = (float*)d_out;

    dendsn_fwd<<<1024, 256, 0, stream>>>(x, k, out);
}

// Round 8
// 19.658 us; speedup vs baseline: 1.6423x; 1.2684x over previous
//
#include <hip/hip_runtime.h>

// DendSN: dendritic spiking neuron forward. FINAL = R2 structure (best).
// x_seq: (T=8, N=16, C=128, H=32, W=32) fp32 ; k: (1,4,1) fp32
// out:   (T=8, N=16, K=32, H=32, W=32) fp32 (0/1 spikes)
//
// Compartment-split across half-waves: lanes 0-31 compute compartments
// {0,1}, lanes 32-63 compute {2,3} for the same sites; dendritic sum
// combined with one __shfl_xor(.,32) per element per step. 16 waves/CU.
// Session evidence: ideal-pattern streaming of this footprint = 12.5 us
// (R6 probe); variants at 8/32 waves/CU, depth-2 prefetch, batched stores
// all regressed -> this is the measured structural optimum (19.8 us).

#define TT 8
#define NB 16
#define CC 128
#define BB 4
#define KK 32
#define LL 1024   // H*W

__global__ __launch_bounds__(256, 4) void dendsn_fwd(
    const float* __restrict__ x, const float* __restrict__ k,
    float* __restrict__ out)
{
    const int tid  = threadIdx.x;
    const int lane = tid & 63;
    const int wv   = tid >> 6;                 // wave index in block (0..3)
    const int half = lane >> 5;                // 0: compartments {0,1}, 1: {2,3}
    const int sl   = lane & 31;

    // pair index: one per (n, kk, l4) spatial 4-group; 2 threads per pair
    const int pairIdx = (blockIdx.x * 4 + wv) * 32 + sl;   // [0, 131072)
    const int l4 = pairIdx & 255;
    const int kk = (pairIdx >> 8) & 31;
    const int n  = pairIdx >> 13;
    const int b0 = half * 2;

    // softmax over the 4 dendritic-strength params, folded with the *3.0
    const float k0 = k[0], k1 = k[1], k2 = k[2], k3 = k[3];
    const float m  = fmaxf(fmaxf(k0, k1), fmaxf(k2, k3));
    const float e0 = expf(k0 - m), e1 = expf(k1 - m),
                e2 = expf(k2 - m), e3 = expf(k3 - m);
    const float inv_s = 1.0f / (e0 + e1 + e2 + e3);
    const float fsa[4] = { 3.0f * e0 * inv_s, 3.0f * e1 * inv_s,
                           3.0f * e2 * inv_s, 3.0f * e3 * inv_s };
    const float fs0 = fsa[b0], fs1 = fsa[b0 + 1];

    // mexican hat constants
    const float v     = 0.75f + 1e-5f;
    const float inv_v = 1.0f / v;
    const float gs    = 1.0f / sqrtf(2.0f * 3.14159265358979323846f * v);

    const size_t tstride_x = (size_t)NB * CC * LL;
    const size_t tstride_o = (size_t)NB * KK * LL;
    const size_t base_x = ((size_t)n * CC + (size_t)kk * BB + b0) * LL
                        + (size_t)l4 * 4;
    const size_t base_o = ((size_t)n * KK + kk) * LL + (size_t)l4 * 4;

    float pre[2][4];   // [local b][j] dendritic filter state
    float h[4];        // somatic LIF state (redundant across halves, exact)
    #pragma unroll
    for (int b = 0; b < 2; ++b)
        #pragma unroll
        for (int j = 0; j < 4; ++j) pre[b][j] = 0.0f;
    #pragma unroll
    for (int j = 0; j < 4; ++j) h[j] = 0.0f;

    // prefetch t=0
    float4 xv[2], xn[2];
    xv[0] = *reinterpret_cast<const float4*>(x + base_x);
    xv[1] = *reinterpret_cast<const float4*>(x + base_x + LL);

    #pragma unroll
    for (int t = 0; t < TT; ++t) {
        if (t + 1 < TT) {   // prefetch next timestep while computing this one
            const size_t bx = base_x + (size_t)(t + 1) * tstride_x;
            xn[0] = *reinterpret_cast<const float4*>(x + bx);
            xn[1] = *reinterpret_cast<const float4*>(x + bx + LL);
        }

        float y[4];
        #pragma unroll
        for (int j = 0; j < 4; ++j) y[j] = 0.0f;
        #pragma unroll
        for (int b = 0; b < 2; ++b) {
            const float xs[4] = { xv[b].x, xv[b].y, xv[b].z, xv[b].w };
            const float fsb = (b == 0) ? fs0 : fs1;
            #pragma unroll
            for (int j = 0; j < 4; ++j) {
                const float p = 0.5f * pre[b][j] + xs[j];   // alpha decay
                pre[b][j] = p;
                const float q = p * p * inv_v;
                const float g = expf(-0.5f * q) * gs;       // gaussian
                y[j] += fsb * ((1.0f - q) * g * inv_v);     // mexican hat
            }
        }

        // combine the two compartment-halves: both halves end with the exact
        // same value (a+b == b+a), so the h recurrence stays bit-identical.
        #pragma unroll
        for (int j = 0; j < 4; ++j)
            y[j] += __shfl_xor(y[j], 32);

        float4 o;
        float* op = &o.x;
        #pragma unroll
        for (int j = 0; j < 4; ++j) {
            const float hh = 0.5f * h[j] + y[j];            // beta decay
            const float s  = (hh - 1.0f >= 0.0f) ? 1.0f : 0.0f;  // heaviside
            h[j] = (s != 0.0f) ? 0.0f : hh;                 // hard reset
            op[j] = s;
        }
        if (half == 0)
            *reinterpret_cast<float4*>(out + base_o + (size_t)t * tstride_o) = o;

        xv[0] = xn[0];
        xv[1] = xn[1];
    }
}

extern "C" void kernel_launch(void* const* d_in, const int* in_sizes, int n_in,
                              void* d_out, int out_size, void* d_ws, size_t ws_size,
                              hipStream_t stream)
{
    const float* x = (const float*)d_in[0];
    const float* k = (const float*)d_in[1];
    float* out = (float*)d_out;

    // 262144 threads (2 per spatial 4-group) -> 1024 blocks of 256
    dendsn_fwd<<<1024, 256, 0, stream>>>(x, k, out);
}